// Round 1
// baseline (465.518 us; speedup 1.0000x reference)
//
#include <hip/hip_runtime.h>

// Resample OLD_SR=4 -> NEW_SR=5, polyphase windowed-sinc, K=56 taps, pad=26 (edge/replicate).
// out[b, n*5+i] = sum_k x[b, clamp(4n + k - 26, 0, T-1)] * kernel[i, k]
// n in [0, 262144) per row (reference truncates the last conv position).

#define OLD_SR  4
#define NEW_SR  5
#define KW      56
#define T_LEN   1048576
#define N_PER_ROW 262144            // output positions n per row
#define OUT_PER_ROW (N_PER_ROW * NEW_SR)  // 1310720
#define R       4                   // consecutive n per thread
#define TPB     256

__global__ __launch_bounds__(TPB) void resample_poly_kernel(
    const float* __restrict__ x,
    const float* __restrict__ krn,   // [NEW_SR][KW] row-major
    float* __restrict__ out)
{
    const int b    = blockIdx.y;
    const int gtid = blockIdx.x * TPB + threadIdx.x;       // [0, N_PER_ROW/R)
    const long long row_in  = (long long)b * T_LEN;
    const long long row_out = (long long)b * OUT_PER_ROW;

    // Window of input covering taps for n = 4*gtid .. 4*gtid+3:
    // needed x indices: [16*gtid - 26, 16*gtid + 41]. Start 2 floats earlier
    // so the base (16*gtid - 28 floats) is 16B-aligned for float4 loads.
    const int g0 = 16 * gtid - 28;

    float w[72];
    if (g0 >= 0 && g0 + 72 <= T_LEN) {
        // fast path: aligned vector loads, no clamping needed
        const float4* xv = reinterpret_cast<const float4*>(x + row_in + g0);
        #pragma unroll
        for (int q = 0; q < 18; ++q) {
            float4 v = xv[q];
            w[4*q+0] = v.x; w[4*q+1] = v.y; w[4*q+2] = v.z; w[4*q+3] = v.w;
        }
    } else {
        // boundary path (first/last 2 threads of a row): clamped scalar loads
        #pragma unroll
        for (int q = 0; q < 72; ++q) {
            int j = g0 + q;
            j = j < 0 ? 0 : (j > T_LEN - 1 ? T_LEN - 1 : j);
            w[q] = x[row_in + j];
        }
    }

    float acc[R * NEW_SR];
    #pragma unroll
    for (int m = 0; m < R * NEW_SR; ++m) acc[m] = 0.0f;

    // coefficients: uniform address, compile-time offsets -> scalar loads (SGPRs)
    #pragma unroll
    for (int k = 0; k < KW; ++k) {
        #pragma unroll
        for (int i = 0; i < NEW_SR; ++i) {
            const float c = krn[i * KW + k];
            #pragma unroll
            for (int r = 0; r < R; ++r) {
                // tap index into w: (4*r + k) + 2  (window shifted by -28 vs -26)
                acc[r * NEW_SR + i] = fmaf(w[4*r + k + 2], c, acc[r * NEW_SR + i]);
            }
        }
    }

    // 20 consecutive output floats per thread, 16B-aligned (gtid*80 bytes)
    float4* ov = reinterpret_cast<float4*>(out + row_out + (long long)gtid * (R * NEW_SR));
    #pragma unroll
    for (int q = 0; q < (R * NEW_SR) / 4; ++q) {
        float4 v;
        v.x = acc[4*q+0]; v.y = acc[4*q+1]; v.z = acc[4*q+2]; v.w = acc[4*q+3];
        ov[q] = v;
    }
}

extern "C" void kernel_launch(void* const* d_in, const int* in_sizes, int n_in,
                              void* d_out, int out_size, void* d_ws, size_t ws_size,
                              hipStream_t stream) {
    const float* x   = (const float*)d_in[0];
    const float* krn = (const float*)d_in[1];
    float* out = (float*)d_out;

    const int B = in_sizes[0] / T_LEN;                 // 32
    dim3 grid(N_PER_ROW / R / TPB, B);                 // (256, 32)
    resample_poly_kernel<<<grid, TPB, 0, stream>>>(x, krn, out);
}

// Round 2
// 299.408 us; speedup vs baseline: 1.5548x; 1.5548x over previous
//
#include <hip/hip_runtime.h>

// Resample OLD_SR=4 -> NEW_SR=5, polyphase windowed-sinc, K=56 taps, pad=26 (edge/replicate).
// out[b, 5n+i] = sum_k x[b, clamp(4n + k - 26, 0, T-1)] * kernel[i, k],  n in [0, 262144)
//
// Structure: block stages its 4152-float input span into LDS (padded +1/16 to kill
// bank conflicts), then each thread computes R=4 consecutive n for all 5 phases,
// reading each of its 68 unique taps from LDS exactly once (tap-ordered FMA).

#define OLD_SR  4
#define NEW_SR  5
#define KW      56
#define T_LEN   1048576
#define N_PER_ROW 262144
#define OUT_PER_ROW (N_PER_ROW * NEW_SR)   // 1310720
#define R       4
#define TPB     256
#define NB      (TPB * R)                  // 1024 output positions n per block
#define SPAN    (NB * OLD_SR)              // 4096 net input floats per block
#define STAGE_N 4152                       // staged floats: sbase = bx*4096 - 28 (16B aligned), idx 0..4151
#define STAGE_V4 (STAGE_N / 4)             // 1038
#define PHYS(i) ((i) + ((i) >> 4))         // +1 pad per 16 floats: lane base stride 17 -> conflict-free
#define LDS_SZ  (PHYS(STAGE_N - 1) + 1)    // 4411 floats = 17.6 KB

__global__ __launch_bounds__(TPB) void resample_poly_kernel(
    const float* __restrict__ x,
    const float* __restrict__ krn,     // [NEW_SR][KW] row-major
    float* __restrict__ out)
{
    __shared__ float lds[LDS_SZ];
    const int tid = threadIdx.x;
    const int bx  = blockIdx.x;                       // [0, N_PER_ROW/NB) = [0,256)
    const int b   = blockIdx.y;
    const long long row_in  = (long long)b * T_LEN;
    const long long row_out = (long long)b * OUT_PER_ROW;
    const int sbase = bx * SPAN - 28;                 // 16B-aligned staging origin

    // ---- stage global -> LDS (padded) ----
    if (sbase >= 0 && sbase + STAGE_N <= T_LEN) {
        // interior block: aligned float4 loads, scalar padded LDS writes
        const float4* xv = reinterpret_cast<const float4*>(x + row_in + sbase);
        for (int q = tid; q < STAGE_V4; q += TPB) {
            float4 v = xv[q];
            int p = PHYS(4 * q);                      // 4q..4q+3 stay inside one 16-group
            lds[p + 0] = v.x;
            lds[p + 1] = v.y;
            lds[p + 2] = v.z;
            lds[p + 3] = v.w;
        }
    } else {
        // first/last block of a row: clamped scalar staging
        for (int s = tid; s < STAGE_N; s += TPB) {
            int g = sbase + s;
            g = g < 0 ? 0 : (g > T_LEN - 1 ? T_LEN - 1 : g);
            lds[PHYS(s)] = x[row_in + g];
        }
    }
    __syncthreads();

    // ---- compute: thread t handles n = bx*NB + 4t .. +3, all 5 phases ----
    float acc[R * NEW_SR];
    #pragma unroll
    for (int m = 0; m < R * NEW_SR; ++m) acc[m] = 0.0f;

    const int pbase = 17 * tid;   // PHYS(16t + c) = 17t + c + (c>>4) for c in [0,70)
    #pragma unroll
    for (int j = 0; j < 68; ++j) {                    // unique tap index j = 4r + k
        const int J = (2 + j) + ((2 + j) >> 4);       // compile-time constant offset
        const float tap = lds[pbase + J];
        #pragma unroll
        for (int r = 0; r < R; ++r) {
            const int k = j - 4 * r;
            if (k >= 0 && k < KW) {
                #pragma unroll
                for (int i = 0; i < NEW_SR; ++i)
                    acc[r * NEW_SR + i] =
                        fmaf(tap, krn[i * KW + k], acc[r * NEW_SR + i]);
            }
        }
    }

    // ---- store: 20 consecutive floats, 16B aligned ----
    float4* ov = reinterpret_cast<float4*>(out + row_out +
                                           (long long)(bx * NB + 4 * tid) * NEW_SR);
    #pragma unroll
    for (int q = 0; q < (R * NEW_SR) / 4; ++q) {
        float4 v;
        v.x = acc[4 * q + 0];
        v.y = acc[4 * q + 1];
        v.z = acc[4 * q + 2];
        v.w = acc[4 * q + 3];
        ov[q] = v;
    }
}

extern "C" void kernel_launch(void* const* d_in, const int* in_sizes, int n_in,
                              void* d_out, int out_size, void* d_ws, size_t ws_size,
                              hipStream_t stream) {
    const float* x   = (const float*)d_in[0];
    const float* krn = (const float*)d_in[1];
    float* out = (float*)d_out;

    const int B = in_sizes[0] / T_LEN;                // 32
    dim3 grid(N_PER_ROW / NB, B);                     // (256, 32)
    resample_poly_kernel<<<grid, TPB, 0, stream>>>(x, krn, out);
}